// Round 1
// 701.188 us; speedup vs baseline: 1.8275x; 1.8275x over previous
//
#include <hip/hip_runtime.h>
#include <math.h>

#define NN 16000     // nodes
#define NE 256000    // edges
#define DIN 256      // input feats
#define NH 8         // heads
#define DH 32        // per-head dim
#define HD 256       // NH*DH

typedef __attribute__((ext_vector_type(8))) __bf16 bf16x8;
typedef __attribute__((ext_vector_type(4))) float f32x4;

union U4 { uint4 u; bf16x8 b; };

__device__ __forceinline__ unsigned bf16pk(float lo, float hi) {
    unsigned a = __float_as_uint(lo), b = __float_as_uint(hi);
    a = (a + 0x7fffu + ((a >> 16) & 1)) >> 16;
    b = (b + 0x7fffu + ((b >> 16) & 1)) >> 16;
    return a | (b << 16);
}

__device__ __forceinline__ float clip5(float x) {
    return fminf(fmaxf(x, -5.0f), 5.0f);
}

// async global->LDS, 16B per lane, dst = wave-uniform base + lane*16
#define GLDS(g, l) __builtin_amdgcn_global_load_lds(                          \
    (const __attribute__((address_space(1))) void*)(g),                       \
    (__attribute__((address_space(3))) void*)(l), 16, 0, 0)

// ---------------------------------------------------------------------------
// Pre-pack Wq,Wk,Wv,We (rows 0..255) to bf16 MFMA-fragment-major layout.
// Chunk c (16B = 8 bf16) within matrix: c = ((ks*16 + NT)*4 + q)*16 + n16
// holds W[ks*32 + q*8 + j][NT*16 + n16], j=0..7.  8192 chunks per matrix.
// ---------------------------------------------------------------------------
__global__ __launch_bounds__(256) void prepack(
    const float* __restrict__ Wq, const float* __restrict__ Wk,
    const float* __restrict__ Wv, const float* __restrict__ We,
    uint4* __restrict__ pack)
{
    int tid = blockIdx.x * 256 + threadIdx.x;   // 0..32767
    int mat = tid >> 13, c = tid & 8191;
    const float* W = (mat == 0) ? Wq : (mat == 1) ? Wk : (mat == 2) ? Wv : We;
    int n16 = c & 15, q = (c >> 4) & 3, NT = (c >> 6) & 15, ks = c >> 10;
    const float* p = &W[(size_t)(ks * 32 + q * 8) * HD + NT * 16 + n16];
    float f0 = p[0],      f1 = p[256],    f2 = p[512],    f3 = p[768];
    float f4 = p[1024],   f5 = p[1280],   f6 = p[1536],   f7 = p[1792];
    uint4 ch;
    ch.x = bf16pk(f0, f1); ch.y = bf16pk(f2, f3);
    ch.z = bf16pk(f4, f5); ch.w = bf16pk(f6, f7);
    pack[tid] = ch;
}

// ---------------------------------------------------------------------------
// QKV: out = x[N,256] @ W[256,256] via bf16 MFMA. 32 rows x 256 cols / block.
// 4 waves; wave w owns cols [w*64, w*64+64) as 2(mt) x 4(nt) 16x16 tiles.
// ---------------------------------------------------------------------------
__global__ __launch_bounds__(256) void qkv_mfma(
    const float* __restrict__ x, const uint4* __restrict__ pack,
    float* __restrict__ Q, float* __restrict__ K, float* __restrict__ V)
{
    __shared__ __align__(16) float s_C[32][260];
    uint4* A_ch = (uint4*)&s_C[0][0];     // 1024 chunks (16KB)
    uint4* B_ch = A_ch + 1024;            // 1024 chunks (16KB)

    const uint4* Bp = pack + (size_t)blockIdx.y * 8192;
    float* out = (blockIdx.y == 0) ? Q : (blockIdx.y == 1) ? K : V;

    const int t = threadIdx.x;
    const int n0 = blockIdx.x * 32;
    const int lane = t & 63, w = t >> 6, quad = lane >> 4, l16 = lane & 15;

    // ---- A staging: fp32 -> bf16 fragment-major ----
    {
        int r = t >> 3, kq = t & 7;
        const float4* src = (const float4*)&x[(size_t)(n0 + r) * DIN + kq * 32];
        float4 f[8];
        #pragma unroll
        for (int i = 0; i < 8; ++i) f[i] = src[i];
        int mt = r >> 4, m16 = r & 15;
        #pragma unroll
        for (int q = 0; q < 4; ++q) {
            uint4 ch;
            ch.x = bf16pk(f[2*q].x,   f[2*q].y);
            ch.y = bf16pk(f[2*q].z,   f[2*q].w);
            ch.z = bf16pk(f[2*q+1].x, f[2*q+1].y);
            ch.w = bf16pk(f[2*q+1].z, f[2*q+1].w);
            A_ch[((kq * 2 + mt) * 4 + q) * 16 + m16] = ch;
        }
    }

    f32x4 acc[2][4];
    #pragma unroll
    for (int mt = 0; mt < 2; ++mt)
        #pragma unroll
        for (int nt = 0; nt < 4; ++nt)
            acc[mt][nt] = (f32x4){0.f, 0.f, 0.f, 0.f};

    for (int ks = 0; ks < 8; ++ks) {
        __syncthreads();                          // prev B consumed / A visible
        const uint4* bp = Bp + ks * 1024 + w * 256 + lane;
        #pragma unroll
        for (int rho = 0; rho < 4; ++rho)
            GLDS(bp + rho * 64, B_ch + (w * 4 + rho) * 64);
        U4 a0, a1;
        a0.u = A_ch[((ks * 2 + 0) * 4 + quad) * 16 + l16];
        a1.u = A_ch[((ks * 2 + 1) * 4 + quad) * 16 + l16];
        __syncthreads();                          // B arrived (vmcnt drained)
        #pragma unroll
        for (int nt = 0; nt < 4; ++nt) {
            U4 b; b.u = B_ch[((w * 4 + nt) * 4 + quad) * 16 + l16];
            acc[0][nt] = __builtin_amdgcn_mfma_f32_16x16x32_bf16(a0.b, b.b, acc[0][nt], 0, 0, 0);
            acc[1][nt] = __builtin_amdgcn_mfma_f32_16x16x32_bf16(a1.b, b.b, acc[1][nt], 0, 0, 0);
        }
    }

    __syncthreads();
    #pragma unroll
    for (int mt = 0; mt < 2; ++mt)
        #pragma unroll
        for (int nt = 0; nt < 4; ++nt)
            #pragma unroll
            for (int reg = 0; reg < 4; ++reg)
                s_C[mt * 16 + quad * 4 + reg][w * 64 + nt * 16 + l16] = acc[mt][nt][reg];
    __syncthreads();

    const int cg = t & 63, rg = t >> 6;
    #pragma unroll
    for (int r = 0; r < 8; ++r) {
        float4 o = *(float4*)&s_C[rg * 8 + r][cg * 4];
        *(float4*)&out[(size_t)(n0 + rg * 8 + r) * HD + cg * 4] = o;
    }
}

// ---------------------------------------------------------------------------
// Edge kernel: ea = [edge_attr | 0.1*dist] @ We via bf16 MFMA, fused attention
// score epilogue. Writes ONLY eout (= alpha). No atomics, no V gather.
// ---------------------------------------------------------------------------
__global__ __launch_bounds__(256) void edge_kernel(
    const float* __restrict__ edge_attr,
    const int*   __restrict__ edge_index,
    const float* __restrict__ coords,
    const uint4* __restrict__ Bp,          // packed We rows 0..255
    const float* __restrict__ We,          // fp32 original (row 256 = dist row)
    const float* __restrict__ Q, const float* __restrict__ K,
    float* __restrict__ eout)
{
    __shared__ __align__(16) float s_C[32][260];
    uint4* A_ch = (uint4*)&s_C[0][0];
    uint4* B_ch = A_ch + 1024;
    __shared__ int   s_row[32], s_col[32];
    __shared__ float s_dist[32];

    const int t = threadIdx.x;
    const int e0 = blockIdx.x * 32;
    const int lane = t & 63, w = t >> 6, quad = lane >> 4, l16 = lane & 15;

    if (t < 32) {
        int e  = e0 + t;
        int nr = edge_index[e];
        int nc = edge_index[NE + e];
        s_row[t] = nr; s_col[t] = nc;
        float dx = coords[nr * 3 + 0] - coords[nc * 3 + 0];
        float dy = coords[nr * 3 + 1] - coords[nc * 3 + 1];
        float dz = coords[nr * 3 + 2] - coords[nc * 3 + 2];
        s_dist[t] = sqrtf(dx * dx + dy * dy + dz * dz) * 0.1f;
    }

    // ---- A staging ----
    {
        int r = t >> 3, kq = t & 7;
        const float4* src =
            (const float4*)&edge_attr[(size_t)(e0 + r) * DIN + kq * 32];
        float4 f[8];
        #pragma unroll
        for (int i = 0; i < 8; ++i) f[i] = src[i];
        int mt = r >> 4, m16 = r & 15;
        #pragma unroll
        for (int q = 0; q < 4; ++q) {
            uint4 ch;
            ch.x = bf16pk(f[2*q].x,   f[2*q].y);
            ch.y = bf16pk(f[2*q].z,   f[2*q].w);
            ch.z = bf16pk(f[2*q+1].x, f[2*q+1].y);
            ch.w = bf16pk(f[2*q+1].z, f[2*q+1].w);
            A_ch[((kq * 2 + mt) * 4 + q) * 16 + m16] = ch;
        }
    }

    f32x4 acc[2][4];
    #pragma unroll
    for (int mt = 0; mt < 2; ++mt)
        #pragma unroll
        for (int nt = 0; nt < 4; ++nt)
            acc[mt][nt] = (f32x4){0.f, 0.f, 0.f, 0.f};

    for (int ks = 0; ks < 8; ++ks) {
        __syncthreads();
        const uint4* bp = Bp + ks * 1024 + w * 256 + lane;
        #pragma unroll
        for (int rho = 0; rho < 4; ++rho)
            GLDS(bp + rho * 64, B_ch + (w * 4 + rho) * 64);
        U4 a0, a1;
        a0.u = A_ch[((ks * 2 + 0) * 4 + quad) * 16 + l16];
        a1.u = A_ch[((ks * 2 + 1) * 4 + quad) * 16 + l16];
        __syncthreads();
        #pragma unroll
        for (int nt = 0; nt < 4; ++nt) {
            U4 b; b.u = B_ch[((w * 4 + nt) * 4 + quad) * 16 + l16];
            acc[0][nt] = __builtin_amdgcn_mfma_f32_16x16x32_bf16(a0.b, b.b, acc[0][nt], 0, 0, 0);
            acc[1][nt] = __builtin_amdgcn_mfma_f32_16x16x32_bf16(a1.b, b.b, acc[1][nt], 0, 0, 0);
        }
    }

    __syncthreads();   // all MFMA inputs consumed; safe to overwrite A/B region
    #pragma unroll
    for (int mt = 0; mt < 2; ++mt)
        #pragma unroll
        for (int nt = 0; nt < 4; ++nt)
            #pragma unroll
            for (int reg = 0; reg < 4; ++reg)
                s_C[mt * 16 + quad * 4 + reg][w * 64 + nt * 16 + l16] = acc[mt][nt][reg];
    __syncthreads();

    // ---- attention score epilogue (thread owns 8 edges x 4 cols) ----
    const float isd = 0.17677669529663687f;       // 1/sqrt(32)
    const int cg = t & 63, rg = t >> 6;
    const int c0 = cg * 4, r0 = rg * 8;
    const float4 wl = *(const float4*)&We[(size_t)256 * HD + c0];  // dist row

    #pragma unroll
    for (int r = 0; r < 8; ++r) {
        int le = r0 + r, e = e0 + le;
        int nr = s_row[le], nc = s_col[le];
        float dd = s_dist[le];
        float4 ea4 = *(float4*)&s_C[le][c0];
        ea4.x += dd * wl.x; ea4.y += dd * wl.y;
        ea4.z += dd * wl.z; ea4.w += dd * wl.w;

        float4 kv = *(const float4*)&K[(size_t)nr * HD + c0];
        float4 qv = *(const float4*)&Q[(size_t)nc * HD + c0];
        float4 al;
        al.x = clip5(kv.x * qv.x * isd) * ea4.x;
        al.y = clip5(kv.y * qv.y * isd) * ea4.y;
        al.z = clip5(kv.z * qv.z * isd) * ea4.z;
        al.w = clip5(kv.w * qv.w * isd) * ea4.w;
        *(float4*)&eout[(size_t)e * HD + c0] = al;
    }
}

// ---------------------------------------------------------------------------
// CSR build by destination node (col).
// ---------------------------------------------------------------------------
__global__ __launch_bounds__(256) void deg_kernel(
    const int* __restrict__ edge_index, int* __restrict__ deg)
{
    int e = blockIdx.x * 256 + threadIdx.x;
    atomicAdd(&deg[edge_index[NE + e]], 1);
}

__global__ __launch_bounds__(1024) void scan_kernel(
    const int* __restrict__ deg, int* __restrict__ offs,
    int* __restrict__ cursor)
{
    __shared__ int s[1024];
    int t = threadIdx.x;
    int base = t * 16;
    int sum = 0;
    #pragma unroll
    for (int i = 0; i < 16; ++i) {
        int idx = base + i;
        sum += (idx < NN) ? deg[idx] : 0;
    }
    s[t] = sum;
    __syncthreads();
    for (int off = 1; off < 1024; off <<= 1) {
        int v = (t >= off) ? s[t - off] : 0;
        __syncthreads();
        s[t] += v;
        __syncthreads();
    }
    int run = (t > 0) ? s[t - 1] : 0;   // exclusive prefix of this chunk
    #pragma unroll
    for (int i = 0; i < 16; ++i) {
        int idx = base + i;
        if (idx < NN) {
            offs[idx] = run;
            cursor[idx] = run;
            run += deg[idx];
        }
    }
    if (t == 1023) offs[NN] = run;      // == NE
}

__global__ __launch_bounds__(256) void scatter_kernel(
    const int* __restrict__ edge_index, int* __restrict__ cursor,
    int* __restrict__ eids)
{
    int e = blockIdx.x * 256 + threadIdx.x;
    int p = atomicAdd(&cursor[edge_index[NE + e]], 1);
    eids[p] = e;
}

// ---------------------------------------------------------------------------
// Aggregation: one block per destination node. Recomputes alphax from eout
// (32-lane shfl reduce per head), accumulates wV & z in registers, writes
// hout = wV/(z+1e-6). No atomics, fully coalesced row reads.
// ---------------------------------------------------------------------------
__global__ __launch_bounds__(256) void agg_kernel(
    const float* __restrict__ V, const float* __restrict__ eout,
    const int* __restrict__ edge_index, const int* __restrict__ offs,
    const int* __restrict__ eids, float* __restrict__ hout)
{
    __shared__ int s_eid[256];
    __shared__ int s_r[256];
    const int n = blockIdx.x, t = threadIdx.x;
    const int beg = offs[n], end = offs[n + 1];
    float acc = 0.f, zs = 0.f;

    for (int base = beg; base < end; base += 256) {
        int m = min(end - base, 256);
        if (t < m) {
            int e = eids[base + t];
            s_eid[t] = e;
            s_r[t] = edge_index[e];      // source node (row)
        }
        __syncthreads();
        // 1-deep software pipeline on the two row loads
        float eo = eout[(size_t)s_eid[0] * HD + t];
        float vv = V[(size_t)s_r[0] * HD + t];
        for (int i = 0; i < m; ++i) {
            float eo_c = eo, vv_c = vv;
            if (i + 1 < m) {
                eo = eout[(size_t)s_eid[i + 1] * HD + t];
                vv = V[(size_t)s_r[i + 1] * HD + t];
            }
            float s = eo_c;              // alpha[e, h, d] at d = t&31
            s += __shfl_xor(s, 1);
            s += __shfl_xor(s, 2);
            s += __shfl_xor(s, 4);
            s += __shfl_xor(s, 8);
            s += __shfl_xor(s, 16);      // sum over d within 32-lane head group
            float a = __expf(clip5(s));
            zs += a;
            acc = fmaf(a, vv_c, acc);
        }
        __syncthreads();
    }
    hout[(size_t)n * HD + t] = acc / (zs + 1e-6f);
}

// ---------------------------------------------------------------------------
extern "C" void kernel_launch(void* const* d_in, const int* in_sizes, int n_in,
                              void* d_out, int out_size, void* d_ws,
                              size_t ws_size, hipStream_t stream)
{
    const float* x         = (const float*)d_in[0];
    const float* edge_attr = (const float*)d_in[1];
    const int*   eidx      = (const int*)d_in[2];
    const float* coords    = (const float*)d_in[3];
    const float* Wq        = (const float*)d_in[4];
    const float* Wk        = (const float*)d_in[5];
    const float* Wv        = (const float*)d_in[6];
    const float* We        = (const float*)d_in[7];

    float* out  = (float*)d_out;
    float* hout = out;                               // [N,256]
    float* eout = out + (size_t)NN * HD;             // [E,256]
    float* cout = eout + (size_t)NE * HD;            // [N,3]

    float* Q = (float*)d_ws;                         // 16.38 MB each
    float* K = Q + (size_t)NN * HD;
    float* V = K + (size_t)NN * HD;
    uint4* pack = (uint4*)(V + (size_t)NN * HD);     // 512 KB @ byte 49,152,000

    // CSR arrays alias the Q region — Q is dead after edge_kernel, and the
    // stream order (qkv -> edge -> memset/hist/scan/scatter -> agg) makes
    // the reuse safe. 1.22 MB total, far under Q's 16.38 MB.
    int* offs   = (int*)d_ws;                        // NN+1
    int* cursor = offs + 16064;
    int* deg    = cursor + 16064;
    int* eids   = deg + 16064;                       // NE ints

    prepack<<<128, 256, 0, stream>>>(Wq, Wk, Wv, We, pack);
    qkv_mfma<<<dim3(NN / 32, 3), 256, 0, stream>>>(x, pack, Q, K, V);
    edge_kernel<<<NE / 32, 256, 0, stream>>>(edge_attr, eidx, coords,
                                             pack + (size_t)3 * 8192, We,
                                             Q, K, eout);
    hipMemsetAsync(deg, 0, NN * sizeof(int), stream);
    deg_kernel<<<NE / 256, 256, 0, stream>>>(eidx, deg);
    scan_kernel<<<1, 1024, 0, stream>>>(deg, offs, cursor);
    scatter_kernel<<<NE / 256, 256, 0, stream>>>(eidx, cursor, eids);
    agg_kernel<<<NN, 256, 0, stream>>>(V, eout, eidx, offs, eids, hout);
    hipMemcpyAsync(cout, coords, (size_t)NN * 3 * sizeof(float),
                   hipMemcpyDeviceToDevice, stream);
}